// Round 14
// baseline (28885.449 us; speedup 1.0000x reference)
//
#include <hip/hip_runtime.h>
#include <hip/hip_fp16.h>

// LSTMTrajectoryEncoder on MI355X.
// Phase 0: compact_kernel — pos[t] = exclusive prefix of mask (masked LSTM
//   steps are exact carry no-ops and are skipped entirely).
// Phase 1: zx_kernel — zx row for active step t written DIRECTLY to compacted
//   slot pos[t], f16, pre-scaled by exp2 gate constants, layout
//   [slot][w*128 + li*8 + a*4 + gate]  (w=unit>>5, a=(unit>>4)&1, li=unit&15)
//   so scan lane (w, li) reads one uint4 = both unit-halves' 4 gates.
// Phase 2: scan_kernel (1 block, 256 thr, 4 waves, 1 wave/SIMD):
//   z = h @ Wh via v_mfma_f32_16x16x32_f16.
//   R13 counters: MfmaUtil = 47% of CU = ~512 MFMA-busy cyc/step for 32
//   MFMAs = 16 cyc each — the compiler issued the 8 chains sequentially,
//   paying dependent-MFMA latency. R14: loop nest swapped (K-tile outer,
//   8 chains inner) so consecutive MFMAs are independent -> ~4.6 cyc issue.
//   C rebuilt fresh each step as splat4(z) (step-local, no AGPR parking);
//   all A rows = h (broadcast) + C splat -> every lane's reg0 is the valid
//   result, own-register readout. Gates redundant per 16-lane group
//   (a = group&1); groups 0-1 publish h. lgkmcnt-only barrier, 2-step
//   unroll + 2-deep zc uint4 prefetch.

#define TT   65536
#define DINN 128
#define HH   128
#define G4   512     // 4*H
#define NEG  0.01f
#define ROWS 16      // t-rows per GEMM block
#define CTH  1024    // compaction threads

#define SC_SIG  (-1.4426950408889634f)   // -log2(e)
#define SC_TANH ( 2.8853900817779268f)   // +2*log2(e)

typedef _Float16 f16x8 __attribute__((ext_vector_type(8)));
typedef float    f32x4 __attribute__((ext_vector_type(4)));

#if defined(__has_builtin)
#if __has_builtin(__builtin_amdgcn_rcpf)
#define RCPF(x) __builtin_amdgcn_rcpf(x)
#endif
#if __has_builtin(__builtin_amdgcn_exp2f)
#define EXP2F(x) __builtin_amdgcn_exp2f(x)
#endif
#endif
#ifndef RCPF
#define RCPF(x) (1.0f / (x))
#endif
#ifndef EXP2F
#define EXP2F(x) exp2f(x)
#endif

#define MF16(a, b, c) __builtin_amdgcn_mfma_f32_16x16x32_f16((a), (b), (c), 0, 0, 0)

// LDS-only barrier: waits DS ops, leaves global loads in flight (no vmcnt drain)
#define LDS_BARRIER() asm volatile("s_waitcnt lgkmcnt(0)\n\ts_barrier" ::: "memory")

// ---------------------------------------------------------- compaction kernel
__global__ __launch_bounds__(CTH) void compact_kernel(
    const int* __restrict__ mask, int* __restrict__ pos, int* __restrict__ cnt_out)
{
    __shared__ int sc[CTH];
    const int th   = threadIdx.x;
    const int base = th * (TT / CTH);
    int cnt = 0;
    #pragma unroll 8
    for (int k = 0; k < TT / CTH; ++k) cnt += (mask[base + k] != 0);
    sc[th] = cnt;
    __syncthreads();
    for (int off = 1; off < CTH; off <<= 1) {      // inclusive Hillis-Steele
        int v = sc[th];
        int u = (th >= off) ? sc[th - off] : 0;
        __syncthreads();
        sc[th] = v + u;
        __syncthreads();
    }
    int p = sc[th] - cnt;                          // exclusive prefix
    for (int k = 0; k < TT / CTH; ++k) {
        int t = base + k;
        pos[t] = p;
        p += (mask[t] != 0);
    }
    if (th == CTH - 1) cnt_out[0] = sc[CTH - 1];
}

// ---------------------------------------------------------------- GEMM kernel
__global__ __launch_bounds__(512) void zx_kernel(
    const float* __restrict__ x, const float* __restrict__ W_in,
    const float* __restrict__ b_in, const float* __restrict__ Wi,
    const float* __restrict__ b_lstm, const int* __restrict__ mask,
    const int* __restrict__ pos, __half* __restrict__ zc)
{
    __shared__ float xt[ROWS][DINN];
    __shared__ float xp[ROWS][DINN];
    const int tid = threadIdx.x;
    const int t0  = blockIdx.x * ROWS;

    {
        const float4* src = (const float4*)(x + (size_t)t0 * DINN);
        ((float4*)&xt[0][0])[tid] = src[tid];
    }
    __syncthreads();

    {
        const int c  = tid & 127;
        const int r0 = tid >> 7;
        float a0 = b_in[c], a1 = a0, a2 = a0, a3 = a0;
        #pragma unroll
        for (int k4 = 0; k4 < DINN / 4; ++k4) {
            const float w0 = W_in[(k4*4+0)*DINN + c];
            const float w1 = W_in[(k4*4+1)*DINN + c];
            const float w2 = W_in[(k4*4+2)*DINN + c];
            const float w3 = W_in[(k4*4+3)*DINN + c];
            float4 v0 = *(const float4*)&xt[r0 +  0][k4*4];
            float4 v1 = *(const float4*)&xt[r0 +  4][k4*4];
            float4 v2 = *(const float4*)&xt[r0 +  8][k4*4];
            float4 v3 = *(const float4*)&xt[r0 + 12][k4*4];
            a0 += v0.x*w0 + v0.y*w1 + v0.z*w2 + v0.w*w3;
            a1 += v1.x*w0 + v1.y*w1 + v1.z*w2 + v1.w*w3;
            a2 += v2.x*w0 + v2.y*w1 + v2.z*w2 + v2.w*w3;
            a3 += v3.x*w0 + v3.y*w1 + v3.z*w2 + v3.w*w3;
        }
        xp[r0 +  0][c] = a0 >= 0.f ? a0 : NEG * a0;
        xp[r0 +  4][c] = a1 >= 0.f ? a1 : NEG * a1;
        xp[r0 +  8][c] = a2 >= 0.f ? a2 : NEG * a2;
        xp[r0 + 12][c] = a3 >= 0.f ? a3 : NEG * a3;
    }
    __syncthreads();

    {
        const int c2 = tid;
        float acc[ROWS];
        const float bl = b_lstm[c2];
        #pragma unroll
        for (int r = 0; r < ROWS; ++r) acc[r] = bl;
        #pragma unroll 4
        for (int k4 = 0; k4 < DINN / 4; ++k4) {
            const float w0 = Wi[(k4*4+0)*G4 + c2];
            const float w1 = Wi[(k4*4+1)*G4 + c2];
            const float w2 = Wi[(k4*4+2)*G4 + c2];
            const float w3 = Wi[(k4*4+3)*G4 + c2];
            #pragma unroll
            for (int r = 0; r < ROWS; ++r) {
                float4 a = *(const float4*)&xp[r][k4*4];
                acc[r] += a.x*w0 + a.y*w1 + a.z*w2 + a.w*w3;
            }
        }
        // c2 = gate*128 + unit; dst = w*128 + li*8 + a*4 + gate (pre-scaled)
        const int   gate = c2 >> 7;
        const int   unit = c2 & 127;
        const int   dst  = (unit >> 5) * 128 + (unit & 15) * 8
                         + ((unit >> 4) & 1) * 4 + gate;
        const float gsc  = (gate == 2) ? SC_TANH : SC_SIG;
        #pragma unroll
        for (int r = 0; r < ROWS; ++r) {
            const int t = t0 + r;
            if (mask[t])
                zc[(size_t)pos[t] * G4 + dst] = __float2half(acc[r] * gsc);
        }
    }
}

// ---------------------------------------------------------------- scan kernel
// 32 B-fragments: bw<g>_<a>_<kt>[j] = Wh[kt*32 + r8 + j][g*128 + 32w + 16a + li]
//                                     * scale(g)
#define DBW(g,a,kt) f16x8 bw##g##_##a##_##kt;
#define LBW(g,a,kt) { f16x8 v_;                                            \
    const float sc_ = ((g) == 2) ? SC_TANH : SC_SIG;                       \
    const int col_ = ((g) << 7) + (w << 5) + ((a) << 4) + li;              \
    _Pragma("unroll")                                                      \
    for (int j_ = 0; j_ < 8; ++j_)                                         \
        v_[j_] = (_Float16)(Wh[((kt)*32 + r8 + j_)*G4 + col_] * sc_);      \
    bw##g##_##a##_##kt = v_; }
#define PBW(g,a,kt) asm volatile("" : "+v"(bw##g##_##a##_##kt));

#define FORKT(M,g,a) M(g,a,0) M(g,a,1) M(g,a,2) M(g,a,3)
#define FORA(M,g)    FORKT(M,g,0) FORKT(M,g,1)
#define FORALLB(M)   FORA(M,0) FORA(M,1) FORA(M,2) FORA(M,3)

// one K-tile advance: 8 INDEPENDENT MFMAs (one per chain) back-to-back
#define KTILE(kt, af) {                                               \
    d00 = MF16(af, bw0_0_##kt, d00);                                  \
    d01 = MF16(af, bw0_1_##kt, d01);                                  \
    d10 = MF16(af, bw1_0_##kt, d10);                                  \
    d11 = MF16(af, bw1_1_##kt, d11);                                  \
    d20 = MF16(af, bw2_0_##kt, d20);                                  \
    d21 = MF16(af, bw2_1_##kt, d21);                                  \
    d30 = MF16(af, bw3_0_##kt, d30);                                  \
    d31 = MF16(af, bw3_1_##kt, d31); }

// one LSTM step
#define STEP(ZZ, PI, PO) {                                            \
    const __half2 qA0 = *(const __half2*)&(ZZ).x;                     \
    const __half2 qA1 = *(const __half2*)&(ZZ).y;                     \
    const __half2 qB0 = *(const __half2*)&(ZZ).z;                     \
    const __half2 qB1 = *(const __half2*)&(ZZ).w;                     \
    const float ziA = __half2float(qA0.x), zfA = __half2float(qA0.y); \
    const float zgA = __half2float(qA1.x), zoA = __half2float(qA1.y); \
    const float ziB = __half2float(qB0.x), zfB = __half2float(qB0.y); \
    const float zgB = __half2float(qB1.x), zoB = __half2float(qB1.y); \
    const __half* hb_ = hbuf[PI];                                     \
    const f16x8 af0 = *(const f16x8*)&hb_[ 0 + r8];                   \
    const f16x8 af1 = *(const f16x8*)&hb_[32 + r8];                   \
    const f16x8 af2 = *(const f16x8*)&hb_[64 + r8];                   \
    const f16x8 af3 = *(const f16x8*)&hb_[96 + r8];                   \
    f32x4 d00 = { ziA, ziA, ziA, ziA };                               \
    f32x4 d01 = { ziB, ziB, ziB, ziB };                               \
    f32x4 d10 = { zfA, zfA, zfA, zfA };                               \
    f32x4 d11 = { zfB, zfB, zfB, zfB };                               \
    f32x4 d20 = { zgA, zgA, zgA, zgA };                               \
    f32x4 d21 = { zgB, zgB, zgB, zgB };                               \
    f32x4 d30 = { zoA, zoA, zoA, zoA };                               \
    f32x4 d31 = { zoB, zoB, zoB, zoB };                               \
    KTILE(0, af0) KTILE(1, af1) KTILE(2, af2) KTILE(3, af3)           \
    const float zi = asel ? d01[0] : d00[0];                          \
    const float zf = asel ? d11[0] : d10[0];                          \
    const float zg = asel ? d21[0] : d20[0];                          \
    const float zo = asel ? d31[0] : d30[0];                          \
    const float i_s = RCPF(1.f + EXP2F(zi));                          \
    const float f_s = RCPF(1.f + EXP2F(zf));                          \
    const float o_s = RCPF(1.f + EXP2F(zo));                          \
    const float g_t = 1.f - 2.f * RCPF(EXP2F(zg) + 1.f);              \
    c_st = f_s * c_st + i_s * g_t;                                    \
    const float t_c = 1.f - 2.f * RCPF(EXP2F(SC_TANH * c_st) + 1.f);  \
    h_st = o_s * t_c;                                                 \
    if (wr) hbuf[PO][uout] = __float2half(h_st);                      \
    LDS_BARRIER();                                                    \
}

__global__ __launch_bounds__(256, 1)
__attribute__((amdgpu_waves_per_eu(1, 1)))
void scan_kernel(
    const __half* __restrict__ zc, const float* __restrict__ Wh,
    const int* __restrict__ cnt, const float* __restrict__ W_lat,
    const float* __restrict__ b_lat, float* __restrict__ out)
{
    const int n    = threadIdx.x;
    const int w    = n >> 6;           // wave: units [32w, 32w+32)
    const int lane = n & 63;
    const int li   = lane & 15;        // column within 16-wide tile
    const int r    = lane >> 4;        // k-group (A/B fragment row-block)
    const int r8   = r << 3;           // k offset of this lane's 8 elements
    const bool asel = (r & 1);         // unit-half this lane's gates use
    const bool wr   = (r < 2);         // groups 0-1 publish h
    const int uout  = (w << 5) + (r << 4) + li;   // unit published (r<2)

    FORALLB(DBW)     // 32 f16x8 weight fragments (128 regs, loop-invariant)
    FORALLB(LBW)     // load + scale + convert
    FORALLB(PBW)     // pin: kill rematerialization

    __shared__ __align__(16) __half hbuf[2][HH];
    __shared__ float hfin[HH];
    ((__half*)hbuf)[n] = __float2half(0.f);   // n<256 covers both buffers
    float c_st = 0.f, h_st = 0.f;
    __syncthreads();

    const int S = cnt[0];
    const uint4* prow = (const uint4*)zc + (w << 4) + li;  // 64 uint4/row
    uint4 z0 = prow[0];
    uint4 z1 = prow[64];
    prow += 128;

    int i = 0;
    for (; i + 1 < S; i += 2) {
        const uint4 za = prow[0];              // 2-deep prefetch
        const uint4 zb = prow[64];
        prow += 128;
        STEP(z0, 0, 1)     // step i   : read hbuf[0], write hbuf[1]
        STEP(z1, 1, 0)     // step i+1 : read hbuf[1], write hbuf[0]
        z0 = za;
        z1 = zb;
    }
    if (i < S) {           // odd tail
        STEP(z0, 0, 1)
    }

    // latent = h_f @ W_lat + b_lat  (fp32 final h for precision)
    if (wr) hfin[uout] = h_st;
    __syncthreads();
    if (n < 16) {
        float acc = b_lat[n];
        #pragma unroll
        for (int k = 0; k < HH; ++k) acc += hfin[k] * W_lat[k * 16 + n];
        out[n] = acc;
    }
}

// ---------------------------------------------------------------- launcher
extern "C" void kernel_launch(void* const* d_in, const int* in_sizes, int n_in,
                              void* d_out, int out_size, void* d_ws, size_t ws_size,
                              hipStream_t stream) {
    const float* x      = (const float*)d_in[0];
    const int*   mask   = (const int*)  d_in[1];
    const float* W_in   = (const float*)d_in[2];
    const float* b_in   = (const float*)d_in[3];
    const float* Wi     = (const float*)d_in[4];
    const float* Wh     = (const float*)d_in[5];
    const float* b_lstm = (const float*)d_in[6];
    const float* W_lat  = (const float*)d_in[7];
    const float* b_lat  = (const float*)d_in[8];
    float* out = (float*)d_out;

    __half* zc  = (__half*)d_ws;                               // (TT+4) rows
    int*    pos = (int*)((char*)d_ws + (size_t)(TT + 4) * G4 * 2);
    int*    cnt = pos + TT;

    compact_kernel<<<1, CTH, 0, stream>>>(mask, pos, cnt);
    zx_kernel<<<TT / ROWS, 512, 0, stream>>>(x, W_in, b_in, Wi, b_lstm,
                                             mask, pos, zc);
    scan_kernel<<<1, 256, 0, stream>>>(zc, Wh, cnt, W_lat, b_lat, out);
}

// Round 15
// 23086.134 us; speedup vs baseline: 1.2512x; 1.2512x over previous
//
#include <hip/hip_runtime.h>
#include <hip/hip_fp16.h>

// LSTMTrajectoryEncoder on MI355X.
// Phase 0: compact_kernel — pos[t] = exclusive prefix of mask (masked LSTM
//   steps are exact carry no-ops and are skipped entirely).
// Phase 1: zx_kernel — zx row for active step t written DIRECTLY to compacted
//   slot pos[t], f16, pre-scaled by exp2 gate constants, layout
//   [slot][w*128 + li*8 + a*4 + gate].
// Phase 2: scan_kernel (1 block, 256 thr, 4 waves, 1 wave/SIMD):
//   z = h @ Wh via v_mfma_f32_16x16x32_f16. R13/R14 established the MFMA
//   phase is at its throughput floor (32 MFMA x 16 SIMD-cyc = 512 cyc/step;
//   ~509 MAC/cyc/SIMD matrix rate, m=1 GEMV). R15 targets the ~485 VALU
//   cyc/step of overhead around it:
//     - loop-invariant pinned zero-C quad seeds all 8 chains (kills 32
//       per-step splat movs / accvgpr writes); z added post-readout.
//     - lanes read only their own unit-half's gates (uint2, 8 B) from zc.
//   R13 chain ordering retained (R14 interleave: same pipe busy, worse regs).
//   Gates redundant per 16-lane group (asel = r&1); groups r<2 publish h.
//   lgkmcnt-only barrier, 2-step unroll + 2-deep zc uint2 prefetch.

#define TT   65536
#define DINN 128
#define HH   128
#define G4   512     // 4*H
#define NEG  0.01f
#define ROWS 16      // t-rows per GEMM block
#define CTH  1024    // compaction threads

#define SC_SIG  (-1.4426950408889634f)   // -log2(e)
#define SC_TANH ( 2.8853900817779268f)   // +2*log2(e)

typedef _Float16 f16x8 __attribute__((ext_vector_type(8)));
typedef float    f32x4 __attribute__((ext_vector_type(4)));

#if defined(__has_builtin)
#if __has_builtin(__builtin_amdgcn_rcpf)
#define RCPF(x) __builtin_amdgcn_rcpf(x)
#endif
#if __has_builtin(__builtin_amdgcn_exp2f)
#define EXP2F(x) __builtin_amdgcn_exp2f(x)
#endif
#endif
#ifndef RCPF
#define RCPF(x) (1.0f / (x))
#endif
#ifndef EXP2F
#define EXP2F(x) exp2f(x)
#endif

#define MF16(a, b, c) __builtin_amdgcn_mfma_f32_16x16x32_f16((a), (b), (c), 0, 0, 0)

// LDS-only barrier: waits DS ops, leaves global loads in flight (no vmcnt drain)
#define LDS_BARRIER() asm volatile("s_waitcnt lgkmcnt(0)\n\ts_barrier" ::: "memory")

// ---------------------------------------------------------- compaction kernel
__global__ __launch_bounds__(CTH) void compact_kernel(
    const int* __restrict__ mask, int* __restrict__ pos, int* __restrict__ cnt_out)
{
    __shared__ int sc[CTH];
    const int th   = threadIdx.x;
    const int base = th * (TT / CTH);
    int cnt = 0;
    #pragma unroll 8
    for (int k = 0; k < TT / CTH; ++k) cnt += (mask[base + k] != 0);
    sc[th] = cnt;
    __syncthreads();
    for (int off = 1; off < CTH; off <<= 1) {      // inclusive Hillis-Steele
        int v = sc[th];
        int u = (th >= off) ? sc[th - off] : 0;
        __syncthreads();
        sc[th] = v + u;
        __syncthreads();
    }
    int p = sc[th] - cnt;                          // exclusive prefix
    for (int k = 0; k < TT / CTH; ++k) {
        int t = base + k;
        pos[t] = p;
        p += (mask[t] != 0);
    }
    if (th == CTH - 1) cnt_out[0] = sc[CTH - 1];
}

// ---------------------------------------------------------------- GEMM kernel
__global__ __launch_bounds__(512) void zx_kernel(
    const float* __restrict__ x, const float* __restrict__ W_in,
    const float* __restrict__ b_in, const float* __restrict__ Wi,
    const float* __restrict__ b_lstm, const int* __restrict__ mask,
    const int* __restrict__ pos, __half* __restrict__ zc)
{
    __shared__ float xt[ROWS][DINN];
    __shared__ float xp[ROWS][DINN];
    const int tid = threadIdx.x;
    const int t0  = blockIdx.x * ROWS;

    {
        const float4* src = (const float4*)(x + (size_t)t0 * DINN);
        ((float4*)&xt[0][0])[tid] = src[tid];
    }
    __syncthreads();

    {
        const int c  = tid & 127;
        const int r0 = tid >> 7;
        float a0 = b_in[c], a1 = a0, a2 = a0, a3 = a0;
        #pragma unroll
        for (int k4 = 0; k4 < DINN / 4; ++k4) {
            const float w0 = W_in[(k4*4+0)*DINN + c];
            const float w1 = W_in[(k4*4+1)*DINN + c];
            const float w2 = W_in[(k4*4+2)*DINN + c];
            const float w3 = W_in[(k4*4+3)*DINN + c];
            float4 v0 = *(const float4*)&xt[r0 +  0][k4*4];
            float4 v1 = *(const float4*)&xt[r0 +  4][k4*4];
            float4 v2 = *(const float4*)&xt[r0 +  8][k4*4];
            float4 v3 = *(const float4*)&xt[r0 + 12][k4*4];
            a0 += v0.x*w0 + v0.y*w1 + v0.z*w2 + v0.w*w3;
            a1 += v1.x*w0 + v1.y*w1 + v1.z*w2 + v1.w*w3;
            a2 += v2.x*w0 + v2.y*w1 + v2.z*w2 + v2.w*w3;
            a3 += v3.x*w0 + v3.y*w1 + v3.z*w2 + v3.w*w3;
        }
        xp[r0 +  0][c] = a0 >= 0.f ? a0 : NEG * a0;
        xp[r0 +  4][c] = a1 >= 0.f ? a1 : NEG * a1;
        xp[r0 +  8][c] = a2 >= 0.f ? a2 : NEG * a2;
        xp[r0 + 12][c] = a3 >= 0.f ? a3 : NEG * a3;
    }
    __syncthreads();

    {
        const int c2 = tid;
        float acc[ROWS];
        const float bl = b_lstm[c2];
        #pragma unroll
        for (int r = 0; r < ROWS; ++r) acc[r] = bl;
        #pragma unroll 4
        for (int k4 = 0; k4 < DINN / 4; ++k4) {
            const float w0 = Wi[(k4*4+0)*G4 + c2];
            const float w1 = Wi[(k4*4+1)*G4 + c2];
            const float w2 = Wi[(k4*4+2)*G4 + c2];
            const float w3 = Wi[(k4*4+3)*G4 + c2];
            #pragma unroll
            for (int r = 0; r < ROWS; ++r) {
                float4 a = *(const float4*)&xp[r][k4*4];
                acc[r] += a.x*w0 + a.y*w1 + a.z*w2 + a.w*w3;
            }
        }
        // c2 = gate*128 + unit; dst = w*128 + li*8 + a*4 + gate (pre-scaled)
        const int   gate = c2 >> 7;
        const int   unit = c2 & 127;
        const int   dst  = (unit >> 5) * 128 + (unit & 15) * 8
                         + ((unit >> 4) & 1) * 4 + gate;
        const float gsc  = (gate == 2) ? SC_TANH : SC_SIG;
        #pragma unroll
        for (int r = 0; r < ROWS; ++r) {
            const int t = t0 + r;
            if (mask[t])
                zc[(size_t)pos[t] * G4 + dst] = __float2half(acc[r] * gsc);
        }
    }
}

// ---------------------------------------------------------------- scan kernel
// 32 B-fragments: bw<g>_<a>_<kt>[j] = Wh[kt*32 + r8 + j][g*128 + 32w + 16a + li]
//                                     * scale(g)
#define DBW(g,a,kt) f16x8 bw##g##_##a##_##kt;
#define LBW(g,a,kt) { f16x8 v_;                                            \
    const float sc_ = ((g) == 2) ? SC_TANH : SC_SIG;                       \
    const int col_ = ((g) << 7) + (w << 5) + ((a) << 4) + li;              \
    _Pragma("unroll")                                                      \
    for (int j_ = 0; j_ < 8; ++j_)                                         \
        v_[j_] = (_Float16)(Wh[((kt)*32 + r8 + j_)*G4 + col_] * sc_);      \
    bw##g##_##a##_##kt = v_; }
#define PBW(g,a,kt) asm volatile("" : "+v"(bw##g##_##a##_##kt));

#define FORKT(M,g,a) M(g,a,0) M(g,a,1) M(g,a,2) M(g,a,3)
#define FORA(M,g)    FORKT(M,g,0) FORKT(M,g,1)
#define FORALLB(M)   FORA(M,0) FORA(M,1) FORA(M,2) FORA(M,3)

// one chain: loop-invariant zero-C, 4 chained MFMAs over K, reg0 readout
#define CHAIN(g,a,zout) {                                             \
    f32x4 d_ = MF16(af0, bw##g##_##a##_0, zq);                        \
    d_ = MF16(af1, bw##g##_##a##_1, d_);                              \
    d_ = MF16(af2, bw##g##_##a##_2, d_);                              \
    d_ = MF16(af3, bw##g##_##a##_3, d_);                              \
    (zout) = d_[0]; }

// one LSTM step; ZZ = uint2 with this lane's half's 4 gates (pre-scaled f16)
#define STEP(ZZ, PI, PO) {                                            \
    const __half2 zl = *(const __half2*)&(ZZ).x;                      \
    const __half2 zh = *(const __half2*)&(ZZ).y;                      \
    const __half* hb_ = hbuf[PI];                                     \
    const f16x8 af0 = *(const f16x8*)&hb_[ 0 + r8];                   \
    const f16x8 af1 = *(const f16x8*)&hb_[32 + r8];                   \
    const f16x8 af2 = *(const f16x8*)&hb_[64 + r8];                   \
    const f16x8 af3 = *(const f16x8*)&hb_[96 + r8];                   \
    float z00, z01, z10, z11, z20, z21, z30, z31;                     \
    CHAIN(0,0,z00) CHAIN(0,1,z01)                                     \
    CHAIN(1,0,z10) CHAIN(1,1,z11)                                     \
    CHAIN(2,0,z20) CHAIN(2,1,z21)                                     \
    CHAIN(3,0,z30) CHAIN(3,1,z31)                                     \
    const float zi = (asel ? z01 : z00) + __half2float(zl.x);         \
    const float zf = (asel ? z11 : z10) + __half2float(zl.y);         \
    const float zg = (asel ? z21 : z20) + __half2float(zh.x);         \
    const float zo = (asel ? z31 : z30) + __half2float(zh.y);         \
    const float i_s = RCPF(1.f + EXP2F(zi));                          \
    const float f_s = RCPF(1.f + EXP2F(zf));                          \
    const float o_s = RCPF(1.f + EXP2F(zo));                          \
    const float g_t = 1.f - 2.f * RCPF(EXP2F(zg) + 1.f);              \
    c_st = f_s * c_st + i_s * g_t;                                    \
    const float t_c = 1.f - 2.f * RCPF(EXP2F(SC_TANH * c_st) + 1.f);  \
    h_st = o_s * t_c;                                                 \
    if (wr) hbuf[PO][uout] = __float2half(h_st);                      \
    LDS_BARRIER();                                                    \
}

__global__ __launch_bounds__(256, 1)
__attribute__((amdgpu_waves_per_eu(1, 1)))
void scan_kernel(
    const __half* __restrict__ zc, const float* __restrict__ Wh,
    const int* __restrict__ cnt, const float* __restrict__ W_lat,
    const float* __restrict__ b_lat, float* __restrict__ out)
{
    const int n    = threadIdx.x;
    const int w    = n >> 6;           // wave: units [32w, 32w+32)
    const int lane = n & 63;
    const int li   = lane & 15;        // column within 16-wide tile
    const int r    = lane >> 4;        // k-group (A/B fragment row-block)
    const int r8   = r << 3;           // k offset of this lane's 8 elements
    const bool asel = (r & 1);         // unit-half this lane's gates use
    const bool wr   = (r < 2);         // groups 0-1 publish h
    const int uout  = (w << 5) + (r << 4) + li;   // unit published (r<2)

    FORALLB(DBW)     // 32 f16x8 weight fragments (128 regs, loop-invariant)
    FORALLB(LBW)     // load + scale + convert
    FORALLB(PBW)     // pin: kill rematerialization

    f32x4 zq = { 0.f, 0.f, 0.f, 0.f };   // loop-invariant zero-C
    asm volatile("" : "+v"(zq));

    __shared__ __align__(16) __half hbuf[2][HH];
    __shared__ float hfin[HH];
    ((__half*)hbuf)[n] = __float2half(0.f);   // n<256 covers both buffers
    float c_st = 0.f, h_st = 0.f;
    __syncthreads();

    const int S = cnt[0];
    // lane reads only its own half's 4 gates: uint2 at w*32 + li*2 + asel
    const uint2* prow = (const uint2*)zc + (w << 5) + (li << 1) + (int)asel;
    uint2 z0 = prow[0];
    uint2 z1 = prow[128];              // 128 uint2 per zc row
    prow += 256;

    int i = 0;
    for (; i + 1 < S; i += 2) {
        const uint2 za = prow[0];      // 2-deep prefetch
        const uint2 zb = prow[128];
        prow += 256;
        STEP(z0, 0, 1)     // step i   : read hbuf[0], write hbuf[1]
        STEP(z1, 1, 0)     // step i+1 : read hbuf[1], write hbuf[0]
        z0 = za;
        z1 = zb;
    }
    if (i < S) {           // odd tail
        STEP(z0, 0, 1)
    }

    // latent = h_f @ W_lat + b_lat  (fp32 final h for precision)
    if (wr) hfin[uout] = h_st;
    __syncthreads();
    if (n < 16) {
        float acc = b_lat[n];
        #pragma unroll
        for (int k = 0; k < HH; ++k) acc += hfin[k] * W_lat[k * 16 + n];
        out[n] = acc;
    }
}

// ---------------------------------------------------------------- launcher
extern "C" void kernel_launch(void* const* d_in, const int* in_sizes, int n_in,
                              void* d_out, int out_size, void* d_ws, size_t ws_size,
                              hipStream_t stream) {
    const float* x      = (const float*)d_in[0];
    const int*   mask   = (const int*)  d_in[1];
    const float* W_in   = (const float*)d_in[2];
    const float* b_in   = (const float*)d_in[3];
    const float* Wi     = (const float*)d_in[4];
    const float* Wh     = (const float*)d_in[5];
    const float* b_lstm = (const float*)d_in[6];
    const float* W_lat  = (const float*)d_in[7];
    const float* b_lat  = (const float*)d_in[8];
    float* out = (float*)d_out;

    __half* zc  = (__half*)d_ws;                               // (TT+4) rows
    int*    pos = (int*)((char*)d_ws + (size_t)(TT + 4) * G4 * 2);
    int*    cnt = pos + TT;

    compact_kernel<<<1, CTH, 0, stream>>>(mask, pos, cnt);
    zx_kernel<<<TT / ROWS, 512, 0, stream>>>(x, W_in, b_in, Wi, b_lstm,
                                             mask, pos, zc);
    scan_kernel<<<1, 256, 0, stream>>>(zc, Wh, cnt, W_lat, b_lat, out);
}